// Round 3
// baseline (132.280 us; speedup 1.0000x reference)
//
#include <hip/hip_runtime.h>
#include <hip/hip_bf16.h>
#include <math.h>

#define N_NODES 8192
#define DIM 256
#define WPR 256   // bitmap words per row = 8192/32
#define MAXD 128  // max deduped neighbors per row (deduped degree ~ Poisson(32); P(>=128) ~ 0)
#define EPS 1e-5f

typedef __attribute__((ext_vector_type(8))) short bf16x8;
typedef __attribute__((ext_vector_type(4))) float f32x4;

// ---------------- kernel 1: init bitmap (diag bits set), degree=1, cols[.][0]=row ----------
// grid: N_NODES*WPR/4/256 = 2048 blocks; each thread writes one uint4 (4 words)
__global__ __launch_bounds__(256) void init_ds(unsigned* __restrict__ bitmap,
                                               int* __restrict__ degree,
                                               int* __restrict__ cols) {
    int t = blockIdx.x * 256 + threadIdx.x;
    int w0 = t * 4;               // first word index
    int row = w0 >> 8;            // 256 words per row; 4 words never straddle rows
    int rel = w0 & 255;
    int diagw = row >> 5;         // word within row holding the diagonal bit
    union { unsigned w[4]; uint4 v; } u;
    u.v = make_uint4(0, 0, 0, 0);
    if (diagw >= rel && diagw < rel + 4)
        u.w[diagw - rel] = 1u << (row & 31);
    ((uint4*)bitmap)[t] = u.v;
    if (rel == 0) { degree[row] = 1; cols[(size_t)row * MAXD] = row; }
}

// ---------------- kernel 2: scatter edges; dedup via atomicOr old-value; build CSR --------
__global__ __launch_bounds__(256) void scatter_edges(const int* __restrict__ erows,
                                                     const int* __restrict__ ecols,
                                                     unsigned* __restrict__ bitmap,
                                                     int* __restrict__ degree,
                                                     int* __restrict__ cols, int E) {
    int e = blockIdx.x * 256 + threadIdx.x;
    if (e >= E) return;
    int r = erows[e];
    int c = ecols[e];
    unsigned bit = 1u << (c & 31);
    unsigned old = atomicOr(&bitmap[(size_t)r * WPR + (c >> 5)], bit);
    if (!(old & bit)) {
        int p = atomicAdd(&degree[r], 1);
        cols[(size_t)r * MAXD + p] = c;
    }
}

// ---------------- kernel 3: convert x and W to bf16 ----------------
__global__ __launch_bounds__(256) void convert_bf16(const float* __restrict__ x,
                                                    const float* __restrict__ W,
                                                    __hip_bfloat16* __restrict__ xb,
                                                    __hip_bfloat16* __restrict__ Wb) {
    size_t i4 = ((size_t)blockIdx.x * 256 + threadIdx.x) * 4;
    const size_t NX = (size_t)N_NODES * DIM;
    const float* src;
    __hip_bfloat16* dst;
    size_t off;
    if (i4 < NX) { src = x; dst = xb; off = i4; }
    else         { src = W; dst = Wb; off = i4 - NX; }
    float4 v = *(const float4*)(src + off);
    union { __hip_bfloat16 h[4]; uint2 u; } t;
    t.h[0] = __float2bfloat16(v.x);
    t.h[1] = __float2bfloat16(v.y);
    t.h[2] = __float2bfloat16(v.z);
    t.h[3] = __float2bfloat16(v.w);
    *(uint2*)(dst + off) = t.u;
}

// ---------------- kernel 4: g = bf16( dinv_m .* (x @ W^T) ) via MFMA ----------------
// grid (128, 4); block 256 = 4 waves; wave computes 16(m) x 64(n)
__global__ __launch_bounds__(256) void gemm_mfma(const short* __restrict__ xb,
                                                 const short* __restrict__ Wb,
                                                 const int* __restrict__ degree,
                                                 __hip_bfloat16* __restrict__ g) {
    int wave = threadIdx.x >> 6;
    int lane = threadIdx.x & 63;
    int bm = blockIdx.x * 64 + wave * 16;
    int bn = blockIdx.y * 64;
    int quad = lane >> 4;
    int l16 = lane & 15;
    f32x4 acc[4] = {};
    const short* arow = xb + (size_t)(bm + l16) * DIM + quad * 8;
#pragma unroll
    for (int k0 = 0; k0 < DIM; k0 += 32) {
        bf16x8 a = *(const bf16x8*)(arow + k0);
#pragma unroll
        for (int s = 0; s < 4; s++) {
            bf16x8 b = *(const bf16x8*)(Wb + (size_t)(bn + s * 16 + l16) * DIM + k0 + quad * 8);
            acc[s] = __builtin_amdgcn_mfma_f32_16x16x32_bf16(a, b, acc[s], 0, 0, 0);
        }
    }
    // C/D layout: col(n) = lane&15, row(m) = quad*4 + r
#pragma unroll
    for (int r = 0; r < 4; r++) {
        int m = bm + quad * 4 + r;
        float s0 = rsqrtf((float)degree[m] + EPS);
#pragma unroll
        for (int s = 0; s < 4; s++)
            g[(size_t)m * DIM + bn + s * 16 + l16] = __float2bfloat16(s0 * acc[s][r]);
    }
}

// ---------------- kernel 5: out[i] = relu(dinv_i * sum_{j in cols(i)} g[j]) -------------
// block 256 = 4 waves; one wave per row; lane owns 4 feats (8 B bf16x4 gathers)
__global__ __launch_bounds__(256) void aggregate(const int* __restrict__ degree,
                                                 const int* __restrict__ cols,
                                                 const uint2* __restrict__ g2,  // row stride 64 uint2
                                                 float* __restrict__ out) {
    int wave = threadIdx.x >> 6;
    int lane = threadIdx.x & 63;
    int row = blockIdx.x * 4 + wave;
    int n = degree[row];                       // wave-uniform -> scalar load
    const int* cl = cols + (size_t)row * MAXD; // wave-uniform base
    float a0[4] = {0.f, 0.f, 0.f, 0.f};
    float a1[4] = {0.f, 0.f, 0.f, 0.f};
    float a2[4] = {0.f, 0.f, 0.f, 0.f};
    float a3[4] = {0.f, 0.f, 0.f, 0.f};
    int i = 0;
    for (; i + 4 <= n; i += 4) {
        int j0 = cl[i], j1 = cl[i + 1], j2 = cl[i + 2], j3 = cl[i + 3];
        uint2 u0 = g2[(size_t)j0 * 64 + lane];
        uint2 u1 = g2[(size_t)j1 * 64 + lane];
        uint2 u2 = g2[(size_t)j2 * 64 + lane];
        uint2 u3 = g2[(size_t)j3 * 64 + lane];
        a0[0] += __uint_as_float(u0.x << 16); a0[1] += __uint_as_float(u0.x & 0xffff0000u);
        a0[2] += __uint_as_float(u0.y << 16); a0[3] += __uint_as_float(u0.y & 0xffff0000u);
        a1[0] += __uint_as_float(u1.x << 16); a1[1] += __uint_as_float(u1.x & 0xffff0000u);
        a1[2] += __uint_as_float(u1.y << 16); a1[3] += __uint_as_float(u1.y & 0xffff0000u);
        a2[0] += __uint_as_float(u2.x << 16); a2[1] += __uint_as_float(u2.x & 0xffff0000u);
        a2[2] += __uint_as_float(u2.y << 16); a2[3] += __uint_as_float(u2.y & 0xffff0000u);
        a3[0] += __uint_as_float(u3.x << 16); a3[1] += __uint_as_float(u3.x & 0xffff0000u);
        a3[2] += __uint_as_float(u3.y << 16); a3[3] += __uint_as_float(u3.y & 0xffff0000u);
    }
    for (; i < n; i++) {
        uint2 u = g2[(size_t)cl[i] * 64 + lane];
        a0[0] += __uint_as_float(u.x << 16); a0[1] += __uint_as_float(u.x & 0xffff0000u);
        a0[2] += __uint_as_float(u.y << 16); a0[3] += __uint_as_float(u.y & 0xffff0000u);
    }
    float s = rsqrtf((float)n + EPS);
    float4 o;
    o.x = fmaxf(s * ((a0[0] + a1[0]) + (a2[0] + a3[0])), 0.f);
    o.y = fmaxf(s * ((a0[1] + a1[1]) + (a2[1] + a3[1])), 0.f);
    o.z = fmaxf(s * ((a0[2] + a1[2]) + (a2[2] + a3[2])), 0.f);
    o.w = fmaxf(s * ((a0[3] + a1[3]) + (a2[3] + a3[3])), 0.f);
    *(float4*)(out + (size_t)row * DIM + lane * 4) = o;
}

extern "C" void kernel_launch(void* const* d_in, const int* in_sizes, int n_in,
                              void* d_out, int out_size, void* d_ws, size_t ws_size,
                              hipStream_t stream) {
    const float* x = (const float*)d_in[0];
    const int* ei = (const int*)d_in[1];   // [2, E] flat: rows then cols
    const float* W = (const float*)d_in[2];
    float* out = (float*)d_out;
    int E = in_sizes[1] / 2;

    unsigned char* ws = (unsigned char*)d_ws;
    size_t off = 0;
    unsigned* bitmap = (unsigned*)(ws + off); off += (size_t)N_NODES * WPR * 4;          // 8 MB
    int* degree = (int*)(ws + off);           off += (size_t)N_NODES * 4;                // 32 KB
    int* cols = (int*)(ws + off);             off += (size_t)N_NODES * MAXD * 4;         // 4 MB
    __hip_bfloat16* xb = (__hip_bfloat16*)(ws + off); off += (size_t)N_NODES * DIM * 2;  // 4 MB
    __hip_bfloat16* Wb = (__hip_bfloat16*)(ws + off); off += (size_t)DIM * DIM * 2;      // 128 KB
    __hip_bfloat16* g = (__hip_bfloat16*)(ws + off);  off += (size_t)N_NODES * DIM * 2;  // 4 MB

    init_ds<<<N_NODES * WPR / 4 / 256, 256, 0, stream>>>(bitmap, degree, cols);
    scatter_edges<<<(E + 255) / 256, 256, 0, stream>>>(ei, ei + E, bitmap, degree, cols, E);
    int conv_threads = (N_NODES * DIM + DIM * DIM) / 4;
    convert_bf16<<<conv_threads / 256, 256, 0, stream>>>(x, W, xb, Wb);
    dim3 ggrid(N_NODES / 64, DIM / 64);
    gemm_mfma<<<ggrid, 256, 0, stream>>>((const short*)xb, (const short*)Wb, degree, g);
    aggregate<<<N_NODES / 4, 256, 0, stream>>>(degree, cols, (const uint2*)g, out);
}

// Round 4
// 123.470 us; speedup vs baseline: 1.0714x; 1.0714x over previous
//
#include <hip/hip_runtime.h>
#include <hip/hip_bf16.h>
#include <math.h>

#define N_NODES 8192
#define DIM 256
#define WPR 256   // bitmap words per row = 8192/32
#define MAXD 128  // max deduped neighbors per row (deduped degree ~ Poisson(33); P(>=128) ~ 0)
#define EPS 1e-5f

typedef __attribute__((ext_vector_type(8))) short bf16x8;
typedef __attribute__((ext_vector_type(4))) float f32x4;

// ---------------- kernel 1: scatter edges + diagonal; dedup via atomicOr; build CSR ------
// threads [0,E) handle edges; threads [E, E+N) push pseudo-edge (i,i).
// Set semantics: exactly one thread sees the 0->1 transition of each bit and appends.
__global__ __launch_bounds__(256) void scatter_all(const int* __restrict__ erows,
                                                   const int* __restrict__ ecols,
                                                   unsigned* __restrict__ bitmap,
                                                   int* __restrict__ degree,
                                                   int* __restrict__ cols, int E) {
    int t = blockIdx.x * 256 + threadIdx.x;
    int r, c;
    if (t < E) {
        r = erows[t];
        c = ecols[t];
    } else if (t < E + N_NODES) {
        r = t - E;
        c = r;
    } else {
        return;
    }
    unsigned bit = 1u << (c & 31);
    unsigned old = atomicOr(&bitmap[(size_t)r * WPR + (c >> 5)], bit);
    if (!(old & bit)) {
        int p = atomicAdd(&degree[r], 1);
        cols[(size_t)r * MAXD + p] = c;
    }
}

// ---------------- pack 8 f32 -> bf16x8 (RNE via __float2bfloat16) ----------------
__device__ inline bf16x8 pack8(float4 lo, float4 hi) {
    union { __hip_bfloat16 h[8]; bf16x8 v; } u;
    u.h[0] = __float2bfloat16(lo.x); u.h[1] = __float2bfloat16(lo.y);
    u.h[2] = __float2bfloat16(lo.z); u.h[3] = __float2bfloat16(lo.w);
    u.h[4] = __float2bfloat16(hi.x); u.h[5] = __float2bfloat16(hi.y);
    u.h[6] = __float2bfloat16(hi.z); u.h[7] = __float2bfloat16(hi.w);
    return u.v;
}

// ---------------- kernel 2: g = bf16( rsqrt(deg) .* (x @ W^T) ) via MFMA ----------------
// grid (128, 4); block 256 = 4 waves; wave computes 16(m) x 64(n); f32->bf16 inline
__global__ __launch_bounds__(256) void gemm_fused(const float* __restrict__ x,
                                                  const float* __restrict__ W,
                                                  const int* __restrict__ degree,
                                                  __hip_bfloat16* __restrict__ g) {
    int wave = threadIdx.x >> 6;
    int lane = threadIdx.x & 63;
    int bm = blockIdx.x * 64 + wave * 16;
    int bn = blockIdx.y * 64;
    int quad = lane >> 4;
    int l16 = lane & 15;
    f32x4 acc[4] = {};
    const float* arow = x + (size_t)(bm + l16) * DIM + quad * 8;
#pragma unroll
    for (int k0 = 0; k0 < DIM; k0 += 32) {
        float4 a0 = *(const float4*)(arow + k0);
        float4 a1 = *(const float4*)(arow + k0 + 4);
        bf16x8 a = pack8(a0, a1);
#pragma unroll
        for (int s = 0; s < 4; s++) {
            const float* brow = W + (size_t)(bn + s * 16 + l16) * DIM + quad * 8 + k0;
            float4 b0 = *(const float4*)(brow);
            float4 b1 = *(const float4*)(brow + 4);
            bf16x8 b = pack8(b0, b1);
            acc[s] = __builtin_amdgcn_mfma_f32_16x16x32_bf16(a, b, acc[s], 0, 0, 0);
        }
    }
    // C/D layout: col(n) = lane&15, row(m) = quad*4 + r
#pragma unroll
    for (int r = 0; r < 4; r++) {
        int m = bm + quad * 4 + r;
        float s0 = rsqrtf((float)degree[m] + EPS);
#pragma unroll
        for (int s = 0; s < 4; s++)
            g[(size_t)m * DIM + bn + s * 16 + l16] = __float2bfloat16(s0 * acc[s][r]);
    }
}

// ---------------- kernel 3: out[i] = relu(rsqrt(deg_i) * sum_{j in cols(i)} g[j]) -------
// block 256 = 4 waves; one wave per row; lane owns 4 feats (8 B bf16x4 gathers);
// indices fetched 4-at-a-time with a single broadcast int4 load.
__global__ __launch_bounds__(256) void aggregate(const int* __restrict__ degree,
                                                 const int* __restrict__ cols,
                                                 const uint2* __restrict__ g2,  // row stride 64 uint2
                                                 float* __restrict__ out) {
    int wave = threadIdx.x >> 6;
    int lane = threadIdx.x & 63;
    int row = blockIdx.x * 4 + wave;
    int n = degree[row];                       // wave-uniform -> scalar load
    const int* cl = cols + (size_t)row * MAXD; // wave-uniform, 512 B aligned
    float a0[4] = {0.f, 0.f, 0.f, 0.f};
    float a1[4] = {0.f, 0.f, 0.f, 0.f};
    float a2[4] = {0.f, 0.f, 0.f, 0.f};
    float a3[4] = {0.f, 0.f, 0.f, 0.f};
    int i = 0;
    for (; i + 4 <= n; i += 4) {
        int4 j4 = *(const int4*)(cl + i);      // one broadcast 16 B load
        uint2 u0 = g2[(size_t)j4.x * 64 + lane];
        uint2 u1 = g2[(size_t)j4.y * 64 + lane];
        uint2 u2 = g2[(size_t)j4.z * 64 + lane];
        uint2 u3 = g2[(size_t)j4.w * 64 + lane];
        a0[0] += __uint_as_float(u0.x << 16); a0[1] += __uint_as_float(u0.x & 0xffff0000u);
        a0[2] += __uint_as_float(u0.y << 16); a0[3] += __uint_as_float(u0.y & 0xffff0000u);
        a1[0] += __uint_as_float(u1.x << 16); a1[1] += __uint_as_float(u1.x & 0xffff0000u);
        a1[2] += __uint_as_float(u1.y << 16); a1[3] += __uint_as_float(u1.y & 0xffff0000u);
        a2[0] += __uint_as_float(u2.x << 16); a2[1] += __uint_as_float(u2.x & 0xffff0000u);
        a2[2] += __uint_as_float(u2.y << 16); a2[3] += __uint_as_float(u2.y & 0xffff0000u);
        a3[0] += __uint_as_float(u3.x << 16); a3[1] += __uint_as_float(u3.x & 0xffff0000u);
        a3[2] += __uint_as_float(u3.y << 16); a3[3] += __uint_as_float(u3.y & 0xffff0000u);
    }
    for (; i < n; i++) {
        uint2 u = g2[(size_t)cl[i] * 64 + lane];
        a0[0] += __uint_as_float(u.x << 16); a0[1] += __uint_as_float(u.x & 0xffff0000u);
        a0[2] += __uint_as_float(u.y << 16); a0[3] += __uint_as_float(u.y & 0xffff0000u);
    }
    float s = rsqrtf((float)n + EPS);
    float4 o;
    o.x = fmaxf(s * ((a0[0] + a1[0]) + (a2[0] + a3[0])), 0.f);
    o.y = fmaxf(s * ((a0[1] + a1[1]) + (a2[1] + a3[1])), 0.f);
    o.z = fmaxf(s * ((a0[2] + a1[2]) + (a2[2] + a3[2])), 0.f);
    o.w = fmaxf(s * ((a0[3] + a1[3]) + (a2[3] + a3[3])), 0.f);
    *(float4*)(out + (size_t)row * DIM + lane * 4) = o;
}

extern "C" void kernel_launch(void* const* d_in, const int* in_sizes, int n_in,
                              void* d_out, int out_size, void* d_ws, size_t ws_size,
                              hipStream_t stream) {
    const float* x = (const float*)d_in[0];
    const int* ei = (const int*)d_in[1];   // [2, E] flat: rows then cols
    const float* W = (const float*)d_in[2];
    float* out = (float*)d_out;
    int E = in_sizes[1] / 2;

    unsigned char* ws = (unsigned char*)d_ws;
    size_t off = 0;
    unsigned* bitmap = (unsigned*)(ws + off); off += (size_t)N_NODES * WPR * 4;          // 8 MB
    int* degree = (int*)(ws + off);           off += (size_t)N_NODES * 4;                // 32 KB (adjacent to bitmap!)
    int* cols = (int*)(ws + off);             off += (size_t)N_NODES * MAXD * 4;         // 4 MB
    __hip_bfloat16* g = (__hip_bfloat16*)(ws + off); off += (size_t)N_NODES * DIM * 2;   // 4 MB

    // one fill covers bitmap + degree (contiguous)
    hipMemsetAsync(bitmap, 0, (size_t)N_NODES * WPR * 4 + (size_t)N_NODES * 4, stream);
    int total = E + N_NODES;
    scatter_all<<<(total + 255) / 256, 256, 0, stream>>>(ei, ei + E, bitmap, degree, cols, E);
    dim3 ggrid(N_NODES / 64, DIM / 64);
    gemm_fused<<<ggrid, 256, 0, stream>>>(x, W, degree, g);
    aggregate<<<N_NODES / 4, 256, 0, stream>>>(degree, cols, (const uint2*)g, out);
}